// Round 1
// baseline (30729.901 us; speedup 1.0000x reference)
//
#include <hip/hip_runtime.h>

// FPS: input [8, 65536, 3] f32 -> (idx [8,1024] (written as f32 values),
//                                  sampled [8,1024,3] f32), concatenated in d_out.
//
// Design: latency-bound sequential argmax. 8 WGs per batch, 1024 thr/WG,
// 8 points/thread held in REGISTERS (px,py,pz,md) -> zero per-round HBM reads.
// Per round: in-register distance update + wave shuffle-reduce + LDS reduce
// across 16 waves, then all-to-all candidate exchange through d_ws with
// agent-scope release/acquire atomics (double-buffered by round parity).
// Every WG redundantly reduces all 8 candidates -> ONE memory round trip
// per round. Tie-breaking: larger min_dist wins, ties -> smaller global index
// (matches np/jnp argmax first-occurrence). Distance arithmetic is
// uncontracted fp32 in reference order for bit-exact argmax decisions.

#define NB    8
#define NPTS  65536
#define NSAMP 1024
#define WPB   8      // workgroups per batch
#define TPB   1024   // threads per workgroup
#define PPT   8      // points per thread  (WPB*TPB*PPT == NPTS)

__global__ __launch_bounds__(TPB)
void fps_kernel(const float* __restrict__ pts, float* __restrict__ out,
                unsigned* __restrict__ ws) {
  const int wg   = blockIdx.x;   // 0..63
  const int b    = wg & 7;       // batch; blocks {b, b+8, ...} -> same XCD (perf only)
  const int w    = wg >> 3;      // wg index within batch, 0..7
  const int tid  = threadIdx.x;
  const int lane = tid & 63;
  const int wave = tid >> 6;     // 0..15

  const float* p = pts + (size_t)b * NPTS * 3;

  // Register-resident points + running min distance.
  float px[PPT], py[PPT], pz[PPT], md[PPT];
#pragma unroll
  for (int i = 0; i < PPT; ++i) {
    const int n = w * (TPB * PPT) + i * TPB + tid;
    px[i] = p[3 * n + 0];
    py[i] = p[3 * n + 1];
    pz[i] = p[3 * n + 2];
    md[i] = 1e10f;               // BIG, matches reference init
  }

  // First selected point is index 0.
  float cx = p[0], cy = p[1], cz = p[2];

  // Workspace per batch: 1024 uints (4 KiB).
  //   tags : [2 parity][8 wg]   at offset 0   (equality-checked vs t+1; 0xAA poison harmless)
  //   slots: [2 parity][8 wg][8] at offset 64 (val, n, x, y, z, pad...)
  unsigned* base = ws + (size_t)b * 1024;

  float* out_idx = out + (size_t)b * NSAMP;
  float* out_smp = out + (size_t)NB * NSAMP + (size_t)b * NSAMP * 3;

  if (w == 0 && tid == 0) {
    out_idx[0] = 0.0f;
    out_smp[0] = cx; out_smp[1] = cy; out_smp[2] = cz;
  }

  __shared__ float red[2][16][5];   // parity-double-buffered wave candidates

  for (int t = 0; t < NSAMP - 1; ++t) {
    // ---- local distance update + thread-local best (first-occurrence ties) ----
    float bv = -1.0f; int bn = 0; float bx = 0.f, by = 0.f, bz = 0.f;
#pragma unroll
    for (int i = 0; i < PPT; ++i) {
      const float dx = __fsub_rn(px[i], cx);
      const float dy = __fsub_rn(py[i], cy);
      const float dz = __fsub_rn(pz[i], cz);
      const float d  = __fadd_rn(__fadd_rn(__fmul_rn(dx, dx), __fmul_rn(dy, dy)),
                                 __fmul_rn(dz, dz));
      const float m = fminf(md[i], d);
      md[i] = m;
      // strict > keeps earliest i (smallest global index) on ties
      if (m > bv) {
        bv = m; bn = w * (TPB * PPT) + i * TPB + tid;
        bx = px[i]; by = py[i]; bz = pz[i];
      }
    }

    // ---- wave butterfly reduce (64 lanes) ----
#pragma unroll
    for (int s = 1; s < 64; s <<= 1) {
      const float ov = __shfl_xor(bv, s, 64);
      const int   on = __shfl_xor(bn, s, 64);
      const float ox = __shfl_xor(bx, s, 64);
      const float oy = __shfl_xor(by, s, 64);
      const float oz = __shfl_xor(bz, s, 64);
      if (ov > bv || (ov == bv && on < bn)) { bv = ov; bn = on; bx = ox; by = oy; bz = oz; }
    }

    const int par = t & 1;
    if (lane == 0) {
      red[par][wave][0] = bv;
      red[par][wave][1] = __int_as_float(bn);
      red[par][wave][2] = bx;
      red[par][wave][3] = by;
      red[par][wave][4] = bz;
    }
    __syncthreads();  // the ONLY barrier per round (also anchors slot-reuse HB chain)

    // ---- wave 0: reduce 16 wave-candidates, publish WG candidate ----
    if (wave == 0) {
      const int e = lane & 15;
      float v  = red[par][e][0];
      int   n2 = __float_as_int(red[par][e][1]);
      float x  = red[par][e][2], y = red[par][e][3], z = red[par][e][4];
#pragma unroll
      for (int s = 1; s < 16; s <<= 1) {
        const float ov = __shfl_xor(v, s, 64);
        const int   on = __shfl_xor(n2, s, 64);
        const float ox = __shfl_xor(x, s, 64);
        const float oy = __shfl_xor(y, s, 64);
        const float oz = __shfl_xor(z, s, 64);
        if (ov > v || (ov == v && on < n2)) { v = ov; n2 = on; x = ox; y = oy; z = oz; }
      }
      if (lane == 0) {
        unsigned* slot = base + 64 + (unsigned)(par * 8 + w) * 8;
        __hip_atomic_store(slot + 0, __float_as_uint(v), __ATOMIC_RELAXED, __HIP_MEMORY_SCOPE_AGENT);
        __hip_atomic_store(slot + 1, (unsigned)n2,        __ATOMIC_RELAXED, __HIP_MEMORY_SCOPE_AGENT);
        __hip_atomic_store(slot + 2, __float_as_uint(x), __ATOMIC_RELAXED, __HIP_MEMORY_SCOPE_AGENT);
        __hip_atomic_store(slot + 3, __float_as_uint(y), __ATOMIC_RELAXED, __HIP_MEMORY_SCOPE_AGENT);
        __hip_atomic_store(slot + 4, __float_as_uint(z), __ATOMIC_RELAXED, __HIP_MEMORY_SCOPE_AGENT);
        // release-tagged: data above is visible before tag flips to t+1
        __hip_atomic_store(base + par * 8 + w, (unsigned)(t + 1), __ATOMIC_RELEASE, __HIP_MEMORY_SCOPE_AGENT);
      }
    }

    // ---- all waves: poll all 8 tags, then reduce the 8 candidates ----
    const unsigned want = (unsigned)(t + 1);
    unsigned* tags = base + par * 8;
    for (;;) {
      const unsigned tg = __hip_atomic_load(tags + (lane & 7), __ATOMIC_ACQUIRE, __HIP_MEMORY_SCOPE_AGENT);
      if (__all(tg == want)) break;
    }
    {
      unsigned* slot = base + 64 + (unsigned)(par * 8 + (lane & 7)) * 8;
      float v  = __uint_as_float(__hip_atomic_load(slot + 0, __ATOMIC_RELAXED, __HIP_MEMORY_SCOPE_AGENT));
      int   n2 = (int)          __hip_atomic_load(slot + 1, __ATOMIC_RELAXED, __HIP_MEMORY_SCOPE_AGENT);
      float x  = __uint_as_float(__hip_atomic_load(slot + 2, __ATOMIC_RELAXED, __HIP_MEMORY_SCOPE_AGENT));
      float y  = __uint_as_float(__hip_atomic_load(slot + 3, __ATOMIC_RELAXED, __HIP_MEMORY_SCOPE_AGENT));
      float z  = __uint_as_float(__hip_atomic_load(slot + 4, __ATOMIC_RELAXED, __HIP_MEMORY_SCOPE_AGENT));
#pragma unroll
      for (int s = 1; s < 8; s <<= 1) {
        const float ov = __shfl_xor(v, s, 64);
        const int   on = __shfl_xor(n2, s, 64);
        const float ox = __shfl_xor(x, s, 64);
        const float oy = __shfl_xor(y, s, 64);
        const float oz = __shfl_xor(z, s, 64);
        if (ov > v || (ov == v && on < n2)) { v = ov; n2 = on; x = ox; y = oy; z = oz; }
      }
      if (w == 0 && tid == 0) {
        out_idx[t + 1] = (float)n2;   // indices are exact in fp32
        out_smp[(t + 1) * 3 + 0] = x;
        out_smp[(t + 1) * 3 + 1] = y;
        out_smp[(t + 1) * 3 + 2] = z;
      }
      cx = x; cy = y; cz = z;
    }
  }
}

extern "C" void kernel_launch(void* const* d_in, const int* in_sizes, int n_in,
                              void* d_out, int out_size, void* d_ws, size_t ws_size,
                              hipStream_t stream) {
  (void)in_sizes; (void)n_in; (void)out_size; (void)ws_size;
  const float* pts = (const float*)d_in[0];
  float* out = (float*)d_out;
  unsigned* ws = (unsigned*)d_ws;
  fps_kernel<<<dim3(NB * WPB), dim3(TPB), 0, stream>>>(pts, out, ws);
}

// Round 2
// 4018.634 us; speedup vs baseline: 7.6469x; 7.6469x over previous
//
#include <hip/hip_runtime.h>

// FPS: input [8, 65536, 3] f32 -> (idx [8,1024] as f32 values, sampled [8,1024,3] f32)
// concatenated flat in d_out.
//
// Latency-bound sequential argmax (1023 rounds). 8 WGs/batch, 1024 thr/WG,
// 8 points/thread in REGISTERS -> zero per-round HBM reads of points.
// Per round:
//   - in-register distance update, thread-local best
//   - 48-bit monotonic key = (dist_bits<<16)|(65535-n): larger dist wins,
//     ties -> smaller index (matches numpy argmax first-occurrence).
//     Distances computed uncontracted fp32 in reference order -> bit-exact.
//   - wave butterfly reduce -> LDS -> wave0 reduces 16 wave candidates
//   - wave0 lane0 publishes a SELF-TAGGED record (3x 64-bit words, each with
//     round tag in low 16 bits) to its 128B-aligned ws slot (parity dbuf).
//     Self-tagging removes the tag->payload dependent load: ONE round trip.
//   - ONLY wave0 (lanes 0..7) polls the 8 records with RELAXED 64-bit atomic
//     loads + s_sleep backoff (64 polling waves total, not 1024 -> no
//     reader-flood starvation of the writer). acq_rel fence once per round
//     makes parity-slot reuse at t+2 race-free.
//   - winner broadcast to the WG through LDS + second __syncthreads.

#define NB    8
#define NPTS  65536
#define NSAMP 1024
#define WPB   8      // workgroups per batch
#define TPB   1024   // threads per workgroup
#define PPT   8      // points per thread (WPB*TPB*PPT == NPTS)
#define RECQ  16     // 16 ull = 128 B per record (own cache line)

typedef unsigned long long ull;

__global__ __launch_bounds__(TPB, 4)
void fps_kernel(const float* __restrict__ pts, float* __restrict__ out,
                ull* __restrict__ ws) {
  const int wg   = blockIdx.x;   // 0..63
  const int b    = wg & 7;       // batch
  const int w    = wg >> 3;      // wg within batch, 0..7
  const int tid  = threadIdx.x;
  const int lane = tid & 63;
  const int wave = tid >> 6;     // 0..15

  const float* p = pts + (size_t)b * NPTS * 3;

  float px[PPT], py[PPT], pz[PPT], md[PPT];
#pragma unroll
  for (int i = 0; i < PPT; ++i) {
    const int n = w * (TPB * PPT) + i * TPB + tid;
    px[i] = p[3 * n + 0];
    py[i] = p[3 * n + 1];
    pz[i] = p[3 * n + 2];
    md[i] = 1e10f;               // BIG, matches reference init
  }

  float cx = p[0], cy = p[1], cz = p[2];   // first pick is index 0

  // ws: per batch 2 parities x 8 records x 128B = 2 KiB (16 KiB total)
  ull* base = ws + (size_t)b * (2 * WPB * RECQ);

  float* out_idx = out + (size_t)b * NSAMP;
  float* out_smp = out + (size_t)NB * NSAMP + (size_t)b * NSAMP * 3;

  if (w == 0 && tid == 0) {
    out_idx[0] = 0.0f;
    out_smp[0] = cx; out_smp[1] = cy; out_smp[2] = cz;
  }

  __shared__ unsigned red[16][5];  // per-wave {key_hi, key_lo, x, y, z}
  __shared__ float bc[3];          // winner xyz broadcast

  for (int t = 0; t < NSAMP - 1; ++t) {
    // ---- local distance update + thread-local best ----
    float bv = -1.0f; int bn = 0; float bx = 0.f, by = 0.f, bz = 0.f;
#pragma unroll
    for (int i = 0; i < PPT; ++i) {
      const float dx = __fsub_rn(px[i], cx);
      const float dy = __fsub_rn(py[i], cy);
      const float dz = __fsub_rn(pz[i], cz);
      const float d  = __fadd_rn(__fadd_rn(__fmul_rn(dx, dx), __fmul_rn(dy, dy)),
                                 __fmul_rn(dz, dz));
      const float m = fminf(md[i], d);
      md[i] = m;
      if (m > bv) {  // strict > keeps earliest i (smallest n) on ties
        bv = m; bn = w * (TPB * PPT) + i * TPB + tid;
        bx = px[i]; by = py[i]; bz = pz[i];
      }
    }
    // monotonic 48-bit key; dist >= 0 so float bits order as uint
    ull key = ((ull)__float_as_uint(bv) << 16) | (ull)(65535 - bn);
    float x = bx, y = by, z = bz;

    // ---- wave butterfly reduce ----
#pragma unroll
    for (int s = 1; s < 64; s <<= 1) {
      const ull   okey = __shfl_xor(key, s, 64);
      const float ox   = __shfl_xor(x, s, 64);
      const float oy   = __shfl_xor(y, s, 64);
      const float oz   = __shfl_xor(z, s, 64);
      if (okey > key) { key = okey; x = ox; y = oy; z = oz; }
    }
    if (lane == 0) {
      red[wave][0] = (unsigned)(key >> 32);
      red[wave][1] = (unsigned)key;
      red[wave][2] = __float_as_uint(x);
      red[wave][3] = __float_as_uint(y);
      red[wave][4] = __float_as_uint(z);
    }
    __syncthreads();

    const ull tag = (ull)(unsigned)(t + 1);   // 1..1023; 0xAAAA poison never matches
    const int par = t & 1;

    if (wave == 0) {
      // ---- reduce 16 wave candidates ----
      const int e = lane & 15;
      ull k2 = ((ull)red[e][0] << 32) | (ull)red[e][1];
      float x2 = __uint_as_float(red[e][2]);
      float y2 = __uint_as_float(red[e][3]);
      float z2 = __uint_as_float(red[e][4]);
#pragma unroll
      for (int s = 1; s < 16; s <<= 1) {
        const ull   okey = __shfl_xor(k2, s, 64);
        const float ox   = __shfl_xor(x2, s, 64);
        const float oy   = __shfl_xor(y2, s, 64);
        const float oz   = __shfl_xor(z2, s, 64);
        if (okey > k2) { k2 = okey; x2 = ox; y2 = oy; z2 = oz; }
      }
      // ---- publish self-tagged record ----
      if (lane == 0) {
        ull* rec = base + (size_t)(par * WPB + w) * RECQ;
        const unsigned xb = __float_as_uint(x2);
        const unsigned yb = __float_as_uint(y2);
        const unsigned zb = __float_as_uint(z2);
        const ull w0 = (k2 << 16) | tag;
        const ull w1 = ((ull)xb << 32) | ((ull)(yb >> 16) << 16) | tag;
        const ull w2 = ((ull)(yb & 0xFFFFu) << 48) | ((ull)zb << 16) | tag;
        __hip_atomic_store(rec + 0, w0, __ATOMIC_RELAXED, __HIP_MEMORY_SCOPE_AGENT);
        __hip_atomic_store(rec + 1, w1, __ATOMIC_RELAXED, __HIP_MEMORY_SCOPE_AGENT);
        __hip_atomic_store(rec + 2, w2, __ATOMIC_RELAXED, __HIP_MEMORY_SCOPE_AGENT);
      }
      // ---- poll all 8 records (lanes 0..7 only; relaxed + backoff) ----
      ull* rec = base + (size_t)(par * WPB + (lane & 7)) * RECQ;
      const bool mine = (lane < WPB);
      bool done = !mine;
      ull r0 = 0, r1 = 0, r2 = 0;
      for (;;) {
        if (!done) {
          r0 = __hip_atomic_load(rec + 0, __ATOMIC_RELAXED, __HIP_MEMORY_SCOPE_AGENT);
          r1 = __hip_atomic_load(rec + 1, __ATOMIC_RELAXED, __HIP_MEMORY_SCOPE_AGENT);
          r2 = __hip_atomic_load(rec + 2, __ATOMIC_RELAXED, __HIP_MEMORY_SCOPE_AGENT);
          done = ((r0 & 0xFFFFull) == tag) & ((r1 & 0xFFFFull) == tag) &
                 ((r2 & 0xFFFFull) == tag);
        }
        if (__all(done)) break;
        __builtin_amdgcn_s_sleep(2);
      }
      // orders this round's poll loads before next rounds' record stores
      // (parity slot reuse at t+2) and any stale-cache concerns
      __builtin_amdgcn_fence(__ATOMIC_ACQ_REL, "agent");

      // ---- decode + reduce 8 candidates (xor groups of 8; lanes>=8 hold 0) ----
      ull   kk = r0 >> 16;
      float xx = __uint_as_float((unsigned)(r1 >> 32));
      float yy = __uint_as_float(((unsigned)((r1 >> 16) & 0xFFFFull) << 16) |
                                 (unsigned)(r2 >> 48));
      float zz = __uint_as_float((unsigned)((r2 >> 16) & 0xFFFFFFFFull));
#pragma unroll
      for (int s = 1; s < 8; s <<= 1) {
        const ull   okey = __shfl_xor(kk, s, 64);
        const float ox   = __shfl_xor(xx, s, 64);
        const float oy   = __shfl_xor(yy, s, 64);
        const float oz   = __shfl_xor(zz, s, 64);
        if (okey > kk) { kk = okey; xx = ox; yy = oy; zz = oz; }
      }
      if (lane == 0) {
        bc[0] = xx; bc[1] = yy; bc[2] = zz;
        if (w == 0) {
          const int n2 = 65535 - (int)(kk & 0xFFFFull);
          out_idx[t + 1] = (float)n2;           // exact in fp32
          out_smp[(t + 1) * 3 + 0] = xx;
          out_smp[(t + 1) * 3 + 1] = yy;
          out_smp[(t + 1) * 3 + 2] = zz;
        }
      }
    }
    __syncthreads();
    cx = bc[0]; cy = bc[1]; cz = bc[2];
  }
}

extern "C" void kernel_launch(void* const* d_in, const int* in_sizes, int n_in,
                              void* d_out, int out_size, void* d_ws, size_t ws_size,
                              hipStream_t stream) {
  (void)in_sizes; (void)n_in; (void)out_size; (void)ws_size;
  const float* pts = (const float*)d_in[0];
  float* out = (float*)d_out;
  ull* ws = (ull*)d_ws;
  fps_kernel<<<dim3(NB * WPB), dim3(TPB), 0, stream>>>(pts, out, ws);
}

// Round 4
// 3945.247 us; speedup vs baseline: 7.7891x; 1.0186x over previous
//
#include <hip/hip_runtime.h>

// FPS: input [8, 65536, 3] f32 -> (idx [8,1024] as f32 values, sampled [8,1024,3] f32)
// concatenated flat in d_out.
//
// Latency-bound sequential argmax (1023 rounds). 8 WGs/batch, 1024 thr/WG,
// 8 points/thread in REGISTERS -> zero per-round HBM point reads.
// Per round:
//   - in-register distance update (uncontracted fp32, reference order ->
//     bit-exact), thread-local best as 48-bit monotonic key
//     (dist_bits<<16 | (65535-n)): larger dist wins, ties -> smaller index
//     (numpy argmax first-occurrence).
//   - KEY-ONLY wave butterfly; unique keys -> exactly one winner lane per
//     wave writes {key,xyz} to LDS. ONE __syncthreads. Wave0 does key-only
//     16-candidate reduce; winner lane publishes a SELF-TAGGED record
//     (3x 64-bit words, round tag in low 16 bits of each) to its 128B ws
//     line (parity double-buffered) with relaxed agent-scope atomics.
//   - ALL 16 waves poll the 8 records (each lane loads record lane&7,
//     relaxed + s_sleep backoff; 8 separate lines -> no reader-flood),
//     xor-8 butterfly with full {key,xyz} carry leaves EVERY lane holding
//     the global winner -> no LDS broadcast, no 2nd barrier.
// Slot reuse at t+2 is ordered by tag transitivity: WG w stores slot(t+2)
// only after seeing every tag(t+1), which exists only after that WG's
// barrier(t+1), which is after all its waves' reads of slot(t) completed.

#define NB    8
#define NPTS  65536
#define NSAMP 1024
#define WPB   8      // workgroups per batch
#define TPB   1024   // threads per workgroup
#define PPT   8      // points per thread (WPB*TPB*PPT == NPTS)
#define RECQ  16     // 16 ull = 128 B per record line

typedef unsigned long long ull;

__global__ __launch_bounds__(TPB, 4)
void fps_kernel(const float* __restrict__ pts, float* __restrict__ out,
                ull* __restrict__ ws) {
  const int wg   = blockIdx.x;   // 0..63
  const int b    = wg & 7;       // batch
  const int w    = wg >> 3;      // wg within batch, 0..7
  const int tid  = threadIdx.x;
  const int lane = tid & 63;
  const int wave = tid >> 6;     // 0..15

  const float* p = pts + (size_t)b * NPTS * 3;

  float px[PPT], py[PPT], pz[PPT], md[PPT];
#pragma unroll
  for (int i = 0; i < PPT; ++i) {
    const int n = w * (TPB * PPT) + i * TPB + tid;
    px[i] = p[3 * n + 0];
    py[i] = p[3 * n + 1];
    pz[i] = p[3 * n + 2];
    md[i] = 1e10f;               // BIG, matches reference init
  }

  float cx = p[0], cy = p[1], cz = p[2];   // first pick is index 0

  // ws: per batch 2 parities x 8 records x 128B = 2 KiB (16 KiB total)
  ull* base = ws + (size_t)b * (2 * WPB * RECQ);

  float* out_idx = out + (size_t)b * NSAMP;
  float* out_smp = out + (size_t)NB * NSAMP + (size_t)b * NSAMP * 3;

  if (w == 0 && tid == 0) {
    out_idx[0] = 0.0f;
    out_smp[0] = cx; out_smp[1] = cy; out_smp[2] = cz;
  }

  __shared__ unsigned red[16][5];  // per-wave {key_hi, key_lo, x, y, z}

  for (int t = 0; t < NSAMP - 1; ++t) {
    // ---- local distance update + thread-local best ----
    float bv = -1.0f; int bn = 0; float bx = 0.f, by = 0.f, bz = 0.f;
#pragma unroll
    for (int i = 0; i < PPT; ++i) {
      const float dx = __fsub_rn(px[i], cx);
      const float dy = __fsub_rn(py[i], cy);
      const float dz = __fsub_rn(pz[i], cz);
      const float d  = __fadd_rn(__fadd_rn(__fmul_rn(dx, dx), __fmul_rn(dy, dy)),
                                 __fmul_rn(dz, dz));
      const float m = fminf(md[i], d);
      md[i] = m;
      if (m > bv) {  // strict > keeps earliest i (smallest n) on ties
        bv = m; bn = w * (TPB * PPT) + i * TPB + tid;
        bx = px[i]; by = py[i]; bz = pz[i];
      }
    }
    // monotonic 48-bit key; dist >= 0 so float bits order as uint; n unique
    const ull key0 = ((ull)__float_as_uint(bv) << 16) | (ull)(65535 - bn);

    // ---- KEY-ONLY wave butterfly; winner lane writes LDS ----
    ull kmax = key0;
#pragma unroll
    for (int s = 1; s < 64; s <<= 1) {
      const ull o = __shfl_xor(kmax, s, 64);
      if (o > kmax) kmax = o;
    }
    if (key0 == kmax) {          // exactly one lane per wave (keys unique)
      red[wave][0] = (unsigned)(key0 >> 32);
      red[wave][1] = (unsigned)key0;
      red[wave][2] = __float_as_uint(bx);
      red[wave][3] = __float_as_uint(by);
      red[wave][4] = __float_as_uint(bz);
    }
    __syncthreads();  // the ONLY barrier per round

    const ull tag = (ull)(unsigned)(t + 1);   // 1..1023; 0xAAAA poison never matches
    const int par = t & 1;

    if (wave == 0) {
      // key-only 16-candidate reduce; winner lane publishes directly
      const int e = lane & 15;
      const ull k2 = ((ull)red[e][0] << 32) | (ull)red[e][1];
      ull k2max = k2;
#pragma unroll
      for (int s = 1; s < 16; s <<= 1) {
        const ull o = __shfl_xor(k2max, s, 64);
        if (o > k2max) k2max = o;
      }
      if (k2 == k2max && lane < 16) {   // exactly one publishing lane
        const unsigned xb = red[e][2];
        const unsigned yb = red[e][3];
        const unsigned zb = red[e][4];
        ull* rec = base + (size_t)(par * WPB + w) * RECQ;
        const ull w0 = (k2 << 16) | tag;
        const ull w1 = ((ull)xb << 32) | ((ull)(yb >> 16) << 16) | tag;
        const ull w2 = ((ull)(yb & 0xFFFFu) << 48) | ((ull)zb << 16) | tag;
        __hip_atomic_store(rec + 0, w0, __ATOMIC_RELAXED, __HIP_MEMORY_SCOPE_AGENT);
        __hip_atomic_store(rec + 1, w1, __ATOMIC_RELAXED, __HIP_MEMORY_SCOPE_AGENT);
        __hip_atomic_store(rec + 2, w2, __ATOMIC_RELAXED, __HIP_MEMORY_SCOPE_AGENT);
      }
    }

    // ---- ALL waves poll; every lane loads record lane&7 ----
    ull r0, r1, r2;
    {
      const ull* rec = base + (size_t)(par * WPB + (lane & 7)) * RECQ;
      for (;;) {
        r0 = __hip_atomic_load(rec + 0, __ATOMIC_RELAXED, __HIP_MEMORY_SCOPE_AGENT);
        r1 = __hip_atomic_load(rec + 1, __ATOMIC_RELAXED, __HIP_MEMORY_SCOPE_AGENT);
        r2 = __hip_atomic_load(rec + 2, __ATOMIC_RELAXED, __HIP_MEMORY_SCOPE_AGENT);
        const bool done = ((r0 & 0xFFFFull) == tag) & ((r1 & 0xFFFFull) == tag) &
                          ((r2 & 0xFFFFull) == tag);
        if (__all(done)) break;
        __builtin_amdgcn_s_sleep(1);
      }
    }

    // ---- decode + xor-8 butterfly with full carry: every lane gets winner ----
    {
      ull   kk = r0 >> 16;
      float xx = __uint_as_float((unsigned)(r1 >> 32));
      float yy = __uint_as_float(((unsigned)((r1 >> 16) & 0xFFFFull) << 16) |
                                 (unsigned)(r2 >> 48));
      float zz = __uint_as_float((unsigned)((r2 >> 16) & 0xFFFFFFFFull));
#pragma unroll
      for (int s = 1; s < 8; s <<= 1) {
        const ull   okey = __shfl_xor(kk, s, 64);
        const float ox   = __shfl_xor(xx, s, 64);
        const float oy   = __shfl_xor(yy, s, 64);
        const float oz   = __shfl_xor(zz, s, 64);
        if (okey > kk) { kk = okey; xx = ox; yy = oy; zz = oz; }
      }
      if (w == 0 && wave == 0 && lane == 0) {
        const int n2 = 65535 - (int)(kk & 0xFFFFull);
        out_idx[t + 1] = (float)n2;           // exact in fp32
        out_smp[(t + 1) * 3 + 0] = xx;
        out_smp[(t + 1) * 3 + 1] = yy;
        out_smp[(t + 1) * 3 + 2] = zz;
      }
      cx = xx; cy = yy; cz = zz;
    }
  }
}

extern "C" void kernel_launch(void* const* d_in, const int* in_sizes, int n_in,
                              void* d_out, int out_size, void* d_ws, size_t ws_size,
                              hipStream_t stream) {
  (void)in_sizes; (void)n_in; (void)out_size; (void)ws_size;
  const float* pts = (const float*)d_in[0];
  float* out = (float*)d_out;
  ull* ws = (ull*)d_ws;
  fps_kernel<<<dim3(NB * WPB), dim3(TPB), 0, stream>>>(pts, out, ws);
}